// Round 1
// 1074.161 us; speedup vs baseline: 1.1172x; 1.1172x over previous
//
#include <hip/hip_runtime.h>
#include <math.h>

typedef unsigned short bfu;                                     // bf16 bit pattern
typedef __attribute__((ext_vector_type(8))) short  bf16x8_t;    // MFMA A/B frag (8 bf16)
typedef __attribute__((ext_vector_type(4))) float  f32x4_t;     // MFMA C/D frag

// fp32 -> bf16 RNE (values are finite; no NaN handling needed)
__device__ __forceinline__ short f2bf(float x){
  unsigned u = __float_as_uint(x);
  u += 0x7fffu + ((u >> 16) & 1u);
  return (short)(u >> 16);
}

// async global->LDS, 16B per lane; LDS dest is wave-uniform base + lane*16
__device__ __forceinline__ void gload_lds16(const void* g, void* l){
  __builtin_amdgcn_global_load_lds((__attribute__((address_space(1))) void*)(g),
                                   (__attribute__((address_space(3))) void*)(l), 16, 0, 0);
}

// ---------------------------------------------------------------------------
// transpose + fp32->bf16 convert: dst[c][r] = bf16(src[r][c])
__global__ __launch_bounds__(256) void k_transpose(const float* __restrict__ src,
                                                   bfu* __restrict__ dst, int R, int C){
  __shared__ float tile[32][33];
  int tx = threadIdx.x & 31, ty = threadIdx.x >> 5;
  int bc = blockIdx.x * 32, br = blockIdx.y * 32;
  #pragma unroll
  for (int i=0;i<4;i++){
    int r = br + ty + i*8, c = bc + tx;
    if (r < R && c < C) tile[ty+i*8][tx] = src[(size_t)r*C + c];
  }
  __syncthreads();
  #pragma unroll
  for (int i=0;i<4;i++){
    int c = bc + ty + i*8, r = br + tx;
    if (c < C && r < R) dst[(size_t)c*R + r] = (bfu)f2bf(tile[tx][ty+i*8]);
  }
}

// ---------------------------------------------------------------------------
// Tiled bf16 MFMA GEMM:  C[M,N] = A[M,K] @ Bt[N,K]^T   (Bt is B transposed)
// AMODE: 0 = A is bf16 (global_load_lds staging)
//        1 = A is fp32 (convert during staging)
//        2 = A is sum of two fp32 buffers (split-K partials) then convert
// EPI:   0 = store fp32 to Cf (+ blockIdx.z*M*N, split-K partial output)
//        1 = bias + tanh -> bf16 Cb
//        2 = bias -> fp32 Cf AND bf16 Cb
// Block tile BM=64*WM x BN=64*WN, 4 waves each computing 64x64, BK=32.
// LDS rows are 32 bf16 = 64B = 4 x 16B slots; content cg of row r lives at
// slot cg ^ ((r>>1)&3)  (XOR swizzle -> frag ds_read_b128 8-way -> 2-way).
// Requires N == BN, M % BM == 0, K % 32 == 0.
template<int WM, int WN, int AMODE, int EPI>
__global__ __launch_bounds__(256) void gemm_kernel(
    const void* __restrict__ Ap, const void* __restrict__ Ap2,
    const bfu* __restrict__ Bt, const float* __restrict__ bias,
    float* __restrict__ Cf, bfu* __restrict__ Cb,
    int M, int N, int K, int Ksub)
{
  constexpr int BM = 64*WM, BN = 64*WN, BK = 32;
  __shared__ bfu As[BM*BK];   // [BM][32] row-major, swizzled slots
  __shared__ bfu Bs[BN*BK];   // [BN][32] row-major, swizzled slots
  const int tid  = threadIdx.x;
  const int lane = tid & 63;
  const int w    = tid >> 6;
  const int wm   = w % WM, wn = w / WM;
  const int q    = lane >> 4, lm = lane & 15;
  const int mBase = blockIdx.x * BM;
  const int kOff0 = blockIdx.z * Ksub;
  float* Cfo = Cf + (size_t)blockIdx.z * M * N;

  // pre-swizzled 16B slot for gload_lds staging (r0 multiples of 16)
  const int cgs = (lane & 3) ^ ((lane >> 3) & 3);

  f32x4_t acc[4][4] = {};

  for (int k0 = 0; k0 < Ksub; k0 += BK){
    const int kOff = kOff0 + k0;
    // ---- stage A tile [BM][32] ----
    if constexpr (AMODE == 0){
      const bfu* A = (const bfu*)Ap;
      #pragma unroll
      for (int i=0;i<BM/64;i++){
        int r0 = w*(BM/4) + i*16;
        gload_lds16(A + (size_t)(mBase + r0 + (lane>>2))*K + kOff + cgs*8,
                    As + r0*BK);
      }
    } else {
      const float* A1 = (const float*)Ap;
      const float* A2 = (const float*)Ap2;
      #pragma unroll
      for (int i=0;i<BM/64;i++){
        int r0 = w*(BM/4) + i*16;
        int r  = r0 + (lane>>2);
        int cc = (lane&3)*8;
        int cw = cgs*8;                     // swizzled LDS slot
        size_t gix = (size_t)(mBase + r)*K + kOff + cc;
        f32x4_t x0 = *(const f32x4_t*)(A1 + gix);
        f32x4_t x1 = *(const f32x4_t*)(A1 + gix + 4);
        if constexpr (AMODE == 2){
          f32x4_t y0 = *(const f32x4_t*)(A2 + gix);
          f32x4_t y1 = *(const f32x4_t*)(A2 + gix + 4);
          x0 += y0; x1 += y1;
        }
        bf16x8_t s;
        #pragma unroll
        for (int e=0;e<4;e++){ s[e] = f2bf(x0[e]); s[e+4] = f2bf(x1[e]); }
        *(bf16x8_t*)(As + r*BK + cw) = s;
      }
    }
    // ---- stage B tile [BN][32] via global_load_lds ----
    #pragma unroll
    for (int i=0;i<BN/64;i++){
      int r0 = w*(BN/4) + i*16;
      gload_lds16(Bt + (size_t)(r0 + (lane>>2))*K + kOff + cgs*8,
                  Bs + r0*BK);
    }
    __syncthreads();
    // ---- MFMA: wave computes 64x64 via 4x4 frags of 16x16x32 ----
    bf16x8_t af[4], bfr[4];
    #pragma unroll
    for (int mf=0;mf<4;mf++){
      int row = wm*64 + mf*16 + lm;
      af[mf]  = *(const bf16x8_t*)(As + row*BK + ((q ^ ((row>>1)&3))*8));
    }
    #pragma unroll
    for (int nf=0;nf<4;nf++){
      int row = wn*64 + nf*16 + lm;
      bfr[nf] = *(const bf16x8_t*)(Bs + row*BK + ((q ^ ((row>>1)&3))*8));
    }
    #pragma unroll
    for (int mf=0;mf<4;mf++)
      #pragma unroll
      for (int nf=0;nf<4;nf++)
        acc[mf][nf] = __builtin_amdgcn_mfma_f32_16x16x32_bf16(af[mf], bfr[nf], acc[mf][nf], 0, 0, 0);
    __syncthreads();
  }
  // ---- epilogue: C/D layout col=lane&15, row=(lane>>4)*4+reg ----
  #pragma unroll
  for (int mf=0;mf<4;mf++){
    #pragma unroll
    for (int nf=0;nf<4;nf++){
      #pragma unroll
      for (int r=0;r<4;r++){
        int row = mBase + wm*64 + mf*16 + q*4 + r;
        int col = wn*64 + nf*16 + lm;       // N == BN
        float v = acc[mf][nf][r];
        size_t oix = (size_t)row*N + col;
        if constexpr (EPI == 0){
          Cfo[oix] = v;
        } else if constexpr (EPI == 1){
          v = tanhf(v + bias[col]);
          Cb[oix] = (bfu)f2bf(v);
        } else {
          v += bias[col];
          Cfo[oix] = v;
          Cb[oix] = (bfu)f2bf(v);
        }
      }
    }
  }
}

// ---------------------------------------------------------------------------
// row squared-norms of E [8192][64] (fp32): one wave per row
__global__ __launch_bounds__(256) void k_n2(const float* __restrict__ E, float* __restrict__ n2){
  int row  = blockIdx.x*4 + (threadIdx.x >> 6);
  int lane = threadIdx.x & 63;
  float v = E[(size_t)row*64 + lane];
  v *= v;
  #pragma unroll
  for (int off=32; off>0; off>>=1) v += __shfl_down(v, off);
  if (lane == 0) n2[row] = v;
}

// ---------------------------------------------------------------------------
// new_force[i][j] = sqrt(max(n2[i]+n2[j]-2*dot(Ei,Ej),0)) * path[i][j]; diag=0
// 128x128 tile per block, Gram via bf16 MFMA (K=64).
// v2: XOR-swizzled E staging (16-way bank conflict -> free) and an
// LDS-transposed epilogue: acc is restaged through a [2][32][132] f32 tile
// (2 passes, aliasing the stage buffers) so path loads / NF stores are
// fully coalesced float4 (1KB per wave instruction).
__global__ __launch_bounds__(256) void k_gram(const bfu* __restrict__ Eb, const float* __restrict__ n2,
                                              const float* __restrict__ path, float* __restrict__ NF)
{
  __shared__ alignas(16) char smraw[33792];           // max(Ei+Ej 32KiB, gram 33KiB)
  bfu*   Ei   = (bfu*)smraw;                          // [128][64] bf16, swizzled
  bfu*   Ej   = (bfu*)(smraw + 16384);                // [128][64] bf16, swizzled
  float* gram = (float*)smraw;                        // [2][32][132] f32
  __shared__ float n2i[128], n2j[128];

  const int tid = threadIdx.x, lane = tid & 63, w = tid >> 6;
  const int ib = blockIdx.x * 128, jb = blockIdx.y * 128;
  if (tid < 128) n2i[tid] = n2[ib + tid];
  else           n2j[tid-128] = n2[jb + tid - 128];

  // ---- stage Ei/Ej: LDS layout puts content cg of row r at slot cg^(r&7)
  // (gload_lds writes linearly -> pre-swizzle the GLOBAL source per lane)
  {
    int rsub = lane >> 3;                 // 0..7 (row within 8-row group)
    int cg   = (lane & 7) ^ rsub;         // 16B slot -> source column group
    #pragma unroll
    for (int i=0;i<4;i++){
      int r0 = w*32 + i*8;                // multiple of 8
      int r  = r0 + rsub;
      gload_lds16(Eb + (size_t)(ib + r)*64 + cg*8, Ei + r0*64);
      gload_lds16(Eb + (size_t)(jb + r)*64 + cg*8, Ej + r0*64);
    }
  }
  __syncthreads();

  const int q = lane >> 4, lm = lane & 15;
  const int wm = w & 1, wn = w >> 1;
  f32x4_t acc[4][4] = {};
  #pragma unroll
  for (int ks=0; ks<2; ks++){
    bf16x8_t af[4], bfr[4];
    #pragma unroll
    for (int mf=0;mf<4;mf++){
      int row = wm*64 + mf*16 + lm;
      int cg  = (ks*4 + q) ^ (row & 7);
      af[mf]  = *(const bf16x8_t*)(Ei + row*64 + cg*8);
    }
    #pragma unroll
    for (int nf=0;nf<4;nf++){
      int row = wn*64 + nf*16 + lm;
      int cg  = (ks*4 + q) ^ (row & 7);
      bfr[nf] = *(const bf16x8_t*)(Ej + row*64 + cg*8);
    }
    #pragma unroll
    for (int mf=0;mf<4;mf++)
      #pragma unroll
      for (int nf=0;nf<4;nf++)
        acc[mf][nf] = __builtin_amdgcn_mfma_f32_16x16x32_bf16(af[mf], bfr[nf], acc[mf][nf], 0, 0, 0);
  }

  // ---- epilogue: 2 passes; pass p covers tile rows {wm*64 + p*32 + 0..31}
  #pragma unroll
  for (int p=0; p<2; p++){
    __syncthreads();                       // stage reads (p=0) / pass reads (p=1) done
    // scatter acc into f32 LDS tile: gram[s=wm][rloc][col], stride 132 (pad)
    #pragma unroll
    for (int mh=0; mh<2; mh++){
      int mf   = 2*p + mh;
      int rbas = mh*16 + q*4;
      #pragma unroll
      for (int nf=0; nf<4; nf++){
        int col = wn*64 + nf*16 + lm;
        #pragma unroll
        for (int r=0;r<4;r++)
          gram[(wm*32 + rbas + r)*132 + col] = acc[mf][nf][r];
      }
    }
    __syncthreads();
    // coalesced sweep: 64 rows x 128 cols, float4 per lane
    #pragma unroll
    for (int it=0; it<8; it++){
      int flat = it*256 + tid;
      int rr   = flat >> 5;                // 0..63
      int s    = rr >> 5;                  // 0..1 (wm half)
      int rloc = rr & 31;
      int colg = (flat & 31)*4;
      int trow = s*64 + p*32 + rloc;
      int gi   = ib + trow;
      int gj   = jb + colg;
      f32x4_t g4 = *(const f32x4_t*)&gram[(s*32 + rloc)*132 + colg];
      f32x4_t nj = *(const f32x4_t*)&n2j[colg];
      float   ni = n2i[trow];
      f32x4_t pv = *(const f32x4_t*)(path + (size_t)gi*8192 + gj);
      f32x4_t outv;
      #pragma unroll
      for (int e=0;e<4;e++){
        float sq = ni + nj[e] - 2.0f*g4[e];
        float dv = sq > 0.0f ? sqrtf(sq) : 0.0f;
        if (gi == gj + e) dv = 0.0f;       // reference diagonal is exactly 0
        outv[e] = dv * pv[e];
      }
      *(f32x4_t*)(NF + (size_t)gi*8192 + gj) = outv;
    }
  }
}

// ---------------------------------------------------------------------------
// Fg[i][c] = sum_j NF[i][j]*members[j][c]; block handles 8 rows, full j-range
__global__ __launch_bounds__(256) void k_fg(const float* __restrict__ NF, const float* __restrict__ mem,
                                            float* __restrict__ Fg){
  const int t = threadIdx.x;
  const int i0 = blockIdx.x * 8;
  float acc[8][8] = {};
  for (int p=0;p<8;p++){
    int j4 = (p*256 + t)*4;
    float mm[4][8];
    #pragma unroll
    for (int qq=0;qq<4;qq++){
      f32x4_t a = *(const f32x4_t*)(mem + (size_t)(j4+qq)*8);
      f32x4_t b = *(const f32x4_t*)(mem + (size_t)(j4+qq)*8 + 4);
      #pragma unroll
      for (int c=0;c<4;c++){ mm[qq][c] = a[c]; mm[qq][c+4] = b[c]; }
    }
    #pragma unroll
    for (int r=0;r<8;r++){
      f32x4_t f = *(const f32x4_t*)(NF + (size_t)(i0+r)*8192 + j4);
      #pragma unroll
      for (int qq=0;qq<4;qq++)
        #pragma unroll
        for (int c=0;c<8;c++)
          acc[r][c] += f[qq]*mm[qq][c];
    }
  }
  __shared__ float red[4][64];
  int lane = t & 63, w = t >> 6;
  #pragma unroll
  for (int rc=0; rc<64; rc++){
    float v = acc[rc>>3][rc&7];
    #pragma unroll
    for (int off=32; off>0; off>>=1) v += __shfl_down(v, off);
    if (lane == 0) red[w][rc] = v;
  }
  __syncthreads();
  if (t < 64) Fg[(size_t)i0*8 + t] = red[0][t]+red[1][t]+red[2][t]+red[3][t];
}

// ---------------------------------------------------------------------------
// d0 partial GEMV: block b covers g in [b*128,b*128+128); 256 thr x 4 outputs
__global__ __launch_bounds__(256) void k_d0(const float* __restrict__ Fg, const float* __restrict__ W,
                                            float* __restrict__ d0a){
  __shared__ float fg[128];
  const int t = threadIdx.x, b = blockIdx.x;
  if (t < 128) fg[t] = Fg[(size_t)b*128 + t];
  __syncthreads();
  const float* Wp = W + (size_t)b*128*1024 + t*4;
  f32x4_t acc = {0.f,0.f,0.f,0.f};
  for (int g=0; g<128; ++g){
    f32x4_t w4 = *(const f32x4_t*)(Wp + (size_t)g*1024);
    acc += w4 * fg[g];
  }
  atomicAdd(&d0a[t*4+0], acc[0]);
  atomicAdd(&d0a[t*4+1], acc[1]);
  atomicAdd(&d0a[t*4+2], acc[2]);
  atomicAdd(&d0a[t*4+3], acc[3]);
}

// d1: relu(d0+b0) @ W_d1 partials (4 blocks over g)
__global__ __launch_bounds__(256) void k_d1(const float* __restrict__ d0a, const float* __restrict__ b0,
                                            const float* __restrict__ W, float* __restrict__ d1a){
  __shared__ float x[256];
  const int t = threadIdx.x, b = blockIdx.x;
  x[t] = fmaxf(d0a[b*256 + t] + b0[b*256 + t], 0.0f);
  __syncthreads();
  float acc = 0.f;
  const float* Wp = W + (size_t)b*256*256 + t;
  for (int g=0; g<256; ++g) acc += x[g] * Wp[(size_t)g*256];
  atomicAdd(&d1a[t], acc);
}

// final: relu(d1+b1) @ W_d2, softmax -> out[8]
__global__ __launch_bounds__(256) void k_final(const float* __restrict__ d1a, const float* __restrict__ b1,
                                               const float* __restrict__ W2, float* __restrict__ outp){
  __shared__ float x[256];
  __shared__ float lg[8];
  const int t = threadIdx.x;
  x[t] = fmaxf(d1a[t] + b1[t], 0.0f);
  __syncthreads();
  if (t < 8){
    float s = 0.f;
    for (int o=0;o<256;o++) s += x[o]*W2[o*8 + t];
    lg[t] = s;
  }
  __syncthreads();
  if (t == 0){
    float mx = lg[0];
    for (int c=1;c<8;c++) mx = fmaxf(mx, lg[c]);
    float e[8], s = 0.f;
    for (int c=0;c<8;c++){ e[c] = expf(lg[c]-mx); s += e[c]; }
    for (int c=0;c<8;c++) outp[c] = e[c]/s;
  }
}

// ---------------------------------------------------------------------------
extern "C" void kernel_launch(void* const* d_in, const int* in_sizes, int n_in,
                              void* d_out, int out_size, void* d_ws, size_t ws_size,
                              hipStream_t stream)
{
  const float* F_   = (const float*)d_in[0];   // [8192,8192]
  const float* X    = (const float*)d_in[1];   // [8192,256]
  const float* We0  = (const float*)d_in[2];   // [256,256]
  const float* be0  = (const float*)d_in[3];
  const float* We1  = (const float*)d_in[4];   // [256,128]
  const float* be1  = (const float*)d_in[5];
  const float* We2  = (const float*)d_in[6];   // [128,64]
  const float* be2  = (const float*)d_in[7];
  const float* Wd0  = (const float*)d_in[8];   // [65536,1024]
  const float* bd0  = (const float*)d_in[9];
  const float* Wd1  = (const float*)d_in[10];  // [1024,256]
  const float* bd1  = (const float*)d_in[11];
  const float* Wd2  = (const float*)d_in[12];  // [256,8]
  const float* path = (const float*)d_in[13];  // [8192,8192]
  const float* mem  = (const float*)d_in[14];  // [8192,8]

  float* out_feat  = (float*)d_out;                       // [8192,64]
  float* out_force = out_feat + (size_t)8192*64;          // [8192,8192]
  float* out_prob  = out_force + (size_t)8192*8192;       // [8]

  char* ws = (char*)d_ws;
  bfu*   XT    = (bfu*)  (ws);             // [256][8192] bf16        4 MiB
  bfu*   We0T  = (bfu*)  (ws + 4194304);   // [256][256]
  bfu*   We1T  = (bfu*)  (ws + 4325376);   // [128][256]
  bfu*   We2T  = (bfu*)  (ws + 4390912);   // [64][128]
  float* partA = (float*)(ws + 4407296);   // 2 x [8192][256] fp32   16 MiB
  bfu*   h0    = (bfu*)  (ws + 21184512);  // [8192][256] bf16
  bfu*   h1    = (bfu*)  (ws + 25378816);  // [8192][128] bf16
  bfu*   Eb    = (bfu*)  (ws + 27475968);  // [8192][64]  bf16
  float* n2    = (float*)(ws + 28524544);  // [8192]
  float* Fg    = (float*)(ws + 28557312);  // [65536]
  float* d0a   = (float*)(ws + 28819456);  // [1024]
  float* d1a   = (float*)(ws + 28823552);  // [256]

  // zero the atomic accumulators (d0a and d1a are adjacent: 4096+1024 bytes)
  hipMemsetAsync(d0a, 0, 5120, stream);

  // bf16 B^T operands
  k_transpose<<<dim3(8,256),256,0,stream>>>(X,   XT,   8192, 256);
  k_transpose<<<dim3(8,8),  256,0,stream>>>(We0, We0T, 256,  256);
  k_transpose<<<dim3(4,8),  256,0,stream>>>(We1, We1T, 256,  128);
  k_transpose<<<dim3(2,4),  256,0,stream>>>(We2, We2T, 128,  64);

  // inp = F_ @ X   (split-K=2, fp32 partials)
  gemm_kernel<1,4,1,0><<<dim3(128,1,2),256,0,stream>>>(F_, nullptr, XT, nullptr,
                                                       partA, nullptr, 8192,256,8192,4096);
  // h0 = tanh(inp @ We0 + b)   (A = sum of split-K partials)
  gemm_kernel<1,4,2,1><<<dim3(128,1,1),256,0,stream>>>(partA, partA + (size_t)8192*256, We0T, be0,
                                                       nullptr, h0, 8192,256,256,256);
  // h1 = tanh(h0 @ We1 + b)
  gemm_kernel<2,2,0,1><<<dim3(64,1,1),256,0,stream>>>(h0, nullptr, We1T, be1,
                                                      nullptr, h1, 8192,128,256,256);
  // E = h1 @ We2 + b  -> fp32 (output 0) and bf16 (for Gram)
  gemm_kernel<4,1,0,2><<<dim3(32,1,1),256,0,stream>>>(h1, nullptr, We2T, be2,
                                                      out_feat, Eb, 8192,64,128,128);

  k_n2<<<2048,256,0,stream>>>(out_feat, n2);
  k_gram<<<dim3(64,64),256,0,stream>>>(Eb, n2, path, out_force);
  k_fg<<<1024,256,0,stream>>>(out_force, mem, Fg);
  k_d0<<<512,256,0,stream>>>(Fg, Wd0, d0a);
  k_d1<<<4,256,0,stream>>>(d0a, bd0, Wd1, d1a);
  k_final<<<1,256,0,stream>>>(d1a, bd1, Wd2, out_prob);
}

// Round 2
// 1073.220 us; speedup vs baseline: 1.1182x; 1.0009x over previous
//
#include <hip/hip_runtime.h>
#include <math.h>

typedef unsigned short bfu;                                     // bf16 bit pattern
typedef __attribute__((ext_vector_type(8))) short  bf16x8_t;    // MFMA A/B frag (8 bf16)
typedef __attribute__((ext_vector_type(4))) float  f32x4_t;     // MFMA C/D frag
typedef __attribute__((ext_vector_type(4))) unsigned short u16x4_t;

// fp32 -> bf16 RNE (values are finite; no NaN handling needed)
__device__ __forceinline__ short f2bf(float x){
  unsigned u = __float_as_uint(x);
  u += 0x7fffu + ((u >> 16) & 1u);
  return (short)(u >> 16);
}

// async global->LDS, 16B per lane; LDS dest is wave-uniform base + lane*16
__device__ __forceinline__ void gload_lds16(const void* g, void* l){
  __builtin_amdgcn_global_load_lds((__attribute__((address_space(1))) void*)(g),
                                   (__attribute__((address_space(3))) void*)(l), 16, 0, 0);
}

// ---------------------------------------------------------------------------
// transpose + fp32->bf16 convert: dst[c][r] = bf16(src[r][c])
__global__ __launch_bounds__(256) void k_transpose(const float* __restrict__ src,
                                                   bfu* __restrict__ dst, int R, int C){
  __shared__ float tile[32][33];
  int tx = threadIdx.x & 31, ty = threadIdx.x >> 5;
  int bc = blockIdx.x * 32, br = blockIdx.y * 32;
  #pragma unroll
  for (int i=0;i<4;i++){
    int r = br + ty + i*8, c = bc + tx;
    if (r < R && c < C) tile[ty+i*8][tx] = src[(size_t)r*C + c];
  }
  __syncthreads();
  #pragma unroll
  for (int i=0;i<4;i++){
    int c = bc + ty + i*8, r = br + tx;
    if (c < C && r < R) dst[(size_t)c*R + r] = (bfu)f2bf(tile[tx][ty+i*8]);
  }
}

// ---------------------------------------------------------------------------
// Tiled bf16 MFMA GEMM:  C[M,N] = A[M,K] @ Bt[N,K]^T   (Bt is B transposed)
// AMODE: 0 = A is bf16 (global_load_lds staging)
//        1 = A is fp32 (convert during staging)
//        2 = A is sum of two fp32 buffers (split-K partials) then convert
// EPI:   0 = store fp32 to Cf (+ blockIdx.z*M*N, split-K partial output)
//        1 = bias + tanh -> bf16 Cb
//        2 = bias -> fp32 Cf AND bf16 Cb
// Block tile BM=64*WM x BN=64*WN, 4 waves each computing 64x64, BK=32.
// LDS rows are 32 bf16 = 64B = 4 x 16B slots; content cg of row r lives at
// slot cg ^ ((r>>1)&3)  (XOR swizzle -> frag ds_read_b128 8-way -> 2-way).
// Requires N == BN, M % BM == 0, K % 32 == 0.
template<int WM, int WN, int AMODE, int EPI>
__global__ __launch_bounds__(256) void gemm_kernel(
    const void* __restrict__ Ap, const void* __restrict__ Ap2,
    const bfu* __restrict__ Bt, const float* __restrict__ bias,
    float* __restrict__ Cf, bfu* __restrict__ Cb,
    int M, int N, int K, int Ksub)
{
  constexpr int BM = 64*WM, BN = 64*WN, BK = 32;
  __shared__ bfu As[BM*BK];   // [BM][32] row-major, swizzled slots
  __shared__ bfu Bs[BN*BK];   // [BN][32] row-major, swizzled slots
  const int tid  = threadIdx.x;
  const int lane = tid & 63;
  const int w    = tid >> 6;
  const int wm   = w % WM, wn = w / WM;
  const int q    = lane >> 4, lm = lane & 15;
  const int mBase = blockIdx.x * BM;
  const int kOff0 = blockIdx.z * Ksub;
  float* Cfo = Cf + (size_t)blockIdx.z * M * N;

  // pre-swizzled 16B slot for gload_lds staging (r0 multiples of 16)
  const int cgs = (lane & 3) ^ ((lane >> 3) & 3);

  f32x4_t acc[4][4] = {};

  for (int k0 = 0; k0 < Ksub; k0 += BK){
    const int kOff = kOff0 + k0;
    // ---- stage A tile [BM][32] ----
    if constexpr (AMODE == 0){
      const bfu* A = (const bfu*)Ap;
      #pragma unroll
      for (int i=0;i<BM/64;i++){
        int r0 = w*(BM/4) + i*16;
        gload_lds16(A + (size_t)(mBase + r0 + (lane>>2))*K + kOff + cgs*8,
                    As + r0*BK);
      }
    } else {
      const float* A1 = (const float*)Ap;
      const float* A2 = (const float*)Ap2;
      #pragma unroll
      for (int i=0;i<BM/64;i++){
        int r0 = w*(BM/4) + i*16;
        int r  = r0 + (lane>>2);
        int cc = (lane&3)*8;
        int cw = cgs*8;                     // swizzled LDS slot
        size_t gix = (size_t)(mBase + r)*K + kOff + cc;
        f32x4_t x0 = *(const f32x4_t*)(A1 + gix);
        f32x4_t x1 = *(const f32x4_t*)(A1 + gix + 4);
        if constexpr (AMODE == 2){
          f32x4_t y0 = *(const f32x4_t*)(A2 + gix);
          f32x4_t y1 = *(const f32x4_t*)(A2 + gix + 4);
          x0 += y0; x1 += y1;
        }
        bf16x8_t s;
        #pragma unroll
        for (int e=0;e<4;e++){ s[e] = f2bf(x0[e]); s[e+4] = f2bf(x1[e]); }
        *(bf16x8_t*)(As + r*BK + cw) = s;
      }
    }
    // ---- stage B tile [BN][32] via global_load_lds ----
    #pragma unroll
    for (int i=0;i<BN/64;i++){
      int r0 = w*(BN/4) + i*16;
      gload_lds16(Bt + (size_t)(r0 + (lane>>2))*K + kOff + cgs*8,
                  Bs + r0*BK);
    }
    __syncthreads();
    // ---- MFMA: wave computes 64x64 via 4x4 frags of 16x16x32 ----
    bf16x8_t af[4], bfr[4];
    #pragma unroll
    for (int mf=0;mf<4;mf++){
      int row = wm*64 + mf*16 + lm;
      af[mf]  = *(const bf16x8_t*)(As + row*BK + ((q ^ ((row>>1)&3))*8));
    }
    #pragma unroll
    for (int nf=0;nf<4;nf++){
      int row = wn*64 + nf*16 + lm;
      bfr[nf] = *(const bf16x8_t*)(Bs + row*BK + ((q ^ ((row>>1)&3))*8));
    }
    #pragma unroll
    for (int mf=0;mf<4;mf++)
      #pragma unroll
      for (int nf=0;nf<4;nf++)
        acc[mf][nf] = __builtin_amdgcn_mfma_f32_16x16x32_bf16(af[mf], bfr[nf], acc[mf][nf], 0, 0, 0);
    __syncthreads();
  }
  // ---- epilogue: C/D layout col=lane&15, row=(lane>>4)*4+reg ----
  #pragma unroll
  for (int mf=0;mf<4;mf++){
    #pragma unroll
    for (int nf=0;nf<4;nf++){
      #pragma unroll
      for (int r=0;r<4;r++){
        int row = mBase + wm*64 + mf*16 + q*4 + r;
        int col = wn*64 + nf*16 + lm;       // N == BN
        float v = acc[mf][nf][r];
        size_t oix = (size_t)row*N + col;
        if constexpr (EPI == 0){
          Cfo[oix] = v;
        } else if constexpr (EPI == 1){
          v = tanhf(v + bias[col]);
          Cb[oix] = (bfu)f2bf(v);
        } else {
          v += bias[col];
          Cfo[oix] = v;
          Cb[oix] = (bfu)f2bf(v);
        }
      }
    }
  }
}

// ---------------------------------------------------------------------------
// sum 8 split-K fp32 partials [8][8192*256] -> bf16 [8192][256]
// one f32x4 per thread, fully coalesced; ~68 MB traffic total
__global__ __launch_bounds__(256) void k_reduce8(const float* __restrict__ P,
                                                 bfu* __restrict__ dst){
  const size_t idx = (size_t)blockIdx.x*256 + threadIdx.x;   // f32x4 index
  const size_t stride4 = (size_t)8192*256/4;                 // f32x4 per partial
  f32x4_t a = *(const f32x4_t*)(P + idx*4);
  #pragma unroll
  for (int s=1;s<8;s++){
    f32x4_t b = *(const f32x4_t*)(P + (stride4*s + idx)*4);
    a += b;
  }
  u16x4_t o;
  #pragma unroll
  for (int e=0;e<4;e++) o[e] = (unsigned short)f2bf(a[e]);
  *(u16x4_t*)(dst + idx*4) = o;
}

// ---------------------------------------------------------------------------
// row squared-norms of E [8192][64] (fp32): one wave per row
__global__ __launch_bounds__(256) void k_n2(const float* __restrict__ E, float* __restrict__ n2){
  int row  = blockIdx.x*4 + (threadIdx.x >> 6);
  int lane = threadIdx.x & 63;
  float v = E[(size_t)row*64 + lane];
  v *= v;
  #pragma unroll
  for (int off=32; off>0; off>>=1) v += __shfl_down(v, off);
  if (lane == 0) n2[row] = v;
}

// ---------------------------------------------------------------------------
// new_force[i][j] = sqrt(max(n2[i]+n2[j]-2*dot(Ei,Ej),0)) * path[i][j]; diag=0
// 128x128 tile per block, Gram via bf16 MFMA (K=64).
// XOR-swizzled E staging (16-way bank conflict -> free) and an
// LDS-transposed epilogue: acc is restaged through a [2][32][132] f32 tile
// (2 passes, aliasing the stage buffers) so path loads / NF stores are
// fully coalesced float4 (1KB per wave instruction).
__global__ __launch_bounds__(256) void k_gram(const bfu* __restrict__ Eb, const float* __restrict__ n2,
                                              const float* __restrict__ path, float* __restrict__ NF)
{
  __shared__ alignas(16) char smraw[33792];           // max(Ei+Ej 32KiB, gram 33KiB)
  bfu*   Ei   = (bfu*)smraw;                          // [128][64] bf16, swizzled
  bfu*   Ej   = (bfu*)(smraw + 16384);                // [128][64] bf16, swizzled
  float* gram = (float*)smraw;                        // [2][32][132] f32
  __shared__ float n2i[128], n2j[128];

  const int tid = threadIdx.x, lane = tid & 63, w = tid >> 6;
  const int ib = blockIdx.x * 128, jb = blockIdx.y * 128;
  if (tid < 128) n2i[tid] = n2[ib + tid];
  else           n2j[tid-128] = n2[jb + tid - 128];

  // ---- stage Ei/Ej: LDS layout puts content cg of row r at slot cg^(r&7)
  // (gload_lds writes linearly -> pre-swizzle the GLOBAL source per lane)
  {
    int rsub = lane >> 3;                 // 0..7 (row within 8-row group)
    int cg   = (lane & 7) ^ rsub;         // 16B slot -> source column group
    #pragma unroll
    for (int i=0;i<4;i++){
      int r0 = w*32 + i*8;                // multiple of 8
      int r  = r0 + rsub;
      gload_lds16(Eb + (size_t)(ib + r)*64 + cg*8, Ei + r0*64);
      gload_lds16(Eb + (size_t)(jb + r)*64 + cg*8, Ej + r0*64);
    }
  }
  __syncthreads();

  const int q = lane >> 4, lm = lane & 15;
  const int wm = w & 1, wn = w >> 1;
  f32x4_t acc[4][4] = {};
  #pragma unroll
  for (int ks=0; ks<2; ks++){
    bf16x8_t af[4], bfr[4];
    #pragma unroll
    for (int mf=0;mf<4;mf++){
      int row = wm*64 + mf*16 + lm;
      int cg  = (ks*4 + q) ^ (row & 7);
      af[mf]  = *(const bf16x8_t*)(Ei + row*64 + cg*8);
    }
    #pragma unroll
    for (int nf=0;nf<4;nf++){
      int row = wn*64 + nf*16 + lm;
      int cg  = (ks*4 + q) ^ (row & 7);
      bfr[nf] = *(const bf16x8_t*)(Ej + row*64 + cg*8);
    }
    #pragma unroll
    for (int mf=0;mf<4;mf++)
      #pragma unroll
      for (int nf=0;nf<4;nf++)
        acc[mf][nf] = __builtin_amdgcn_mfma_f32_16x16x32_bf16(af[mf], bfr[nf], acc[mf][nf], 0, 0, 0);
  }

  // ---- epilogue: 2 passes; pass p covers tile rows {wm*64 + p*32 + 0..31}
  #pragma unroll
  for (int p=0; p<2; p++){
    __syncthreads();                       // stage reads (p=0) / pass reads (p=1) done
    // scatter acc into f32 LDS tile: gram[s=wm][rloc][col], stride 132 (pad)
    #pragma unroll
    for (int mh=0; mh<2; mh++){
      int mf   = 2*p + mh;
      int rbas = mh*16 + q*4;
      #pragma unroll
      for (int nf=0; nf<4; nf++){
        int col = wn*64 + nf*16 + lm;
        #pragma unroll
        for (int r=0;r<4;r++)
          gram[(wm*32 + rbas + r)*132 + col] = acc[mf][nf][r];
      }
    }
    __syncthreads();
    // coalesced sweep: 64 rows x 128 cols, float4 per lane
    #pragma unroll
    for (int it=0; it<8; it++){
      int flat = it*256 + tid;
      int rr   = flat >> 5;                // 0..63
      int s    = rr >> 5;                  // 0..1 (wm half)
      int rloc = rr & 31;
      int colg = (flat & 31)*4;
      int trow = s*64 + p*32 + rloc;
      int gi   = ib + trow;
      int gj   = jb + colg;
      f32x4_t g4 = *(const f32x4_t*)&gram[(s*32 + rloc)*132 + colg];
      f32x4_t nj = *(const f32x4_t*)&n2j[colg];
      float   ni = n2i[trow];
      f32x4_t pv = *(const f32x4_t*)(path + (size_t)gi*8192 + gj);
      f32x4_t outv;
      #pragma unroll
      for (int e=0;e<4;e++){
        float sq = ni + nj[e] - 2.0f*g4[e];
        float dv = sq > 0.0f ? sqrtf(sq) : 0.0f;
        if (gi == gj + e) dv = 0.0f;       // reference diagonal is exactly 0
        outv[e] = dv * pv[e];
      }
      *(f32x4_t*)(NF + (size_t)gi*8192 + gj) = outv;
    }
  }
}

// ---------------------------------------------------------------------------
// Fg[i][c] = sum_j NF[i][j]*members[j][c]; block handles 8 rows, full j-range
__global__ __launch_bounds__(256) void k_fg(const float* __restrict__ NF, const float* __restrict__ mem,
                                            float* __restrict__ Fg){
  const int t = threadIdx.x;
  const int i0 = blockIdx.x * 8;
  float acc[8][8] = {};
  for (int p=0;p<8;p++){
    int j4 = (p*256 + t)*4;
    float mm[4][8];
    #pragma unroll
    for (int qq=0;qq<4;qq++){
      f32x4_t a = *(const f32x4_t*)(mem + (size_t)(j4+qq)*8);
      f32x4_t b = *(const f32x4_t*)(mem + (size_t)(j4+qq)*8 + 4);
      #pragma unroll
      for (int c=0;c<4;c++){ mm[qq][c] = a[c]; mm[qq][c+4] = b[c]; }
    }
    #pragma unroll
    for (int r=0;r<8;r++){
      f32x4_t f = *(const f32x4_t*)(NF + (size_t)(i0+r)*8192 + j4);
      #pragma unroll
      for (int qq=0;qq<4;qq++)
        #pragma unroll
        for (int c=0;c<8;c++)
          acc[r][c] += f[qq]*mm[qq][c];
    }
  }
  __shared__ float red[4][64];
  int lane = t & 63, w = t >> 6;
  #pragma unroll
  for (int rc=0; rc<64; rc++){
    float v = acc[rc>>3][rc&7];
    #pragma unroll
    for (int off=32; off>0; off>>=1) v += __shfl_down(v, off);
    if (lane == 0) red[w][rc] = v;
  }
  __syncthreads();
  if (t < 64) Fg[(size_t)i0*8 + t] = red[0][t]+red[1][t]+red[2][t]+red[3][t];
}

// ---------------------------------------------------------------------------
// d0 partial GEMV: block b covers g in [b*128,b*128+128); 256 thr x 4 outputs
__global__ __launch_bounds__(256) void k_d0(const float* __restrict__ Fg, const float* __restrict__ W,
                                            float* __restrict__ d0a){
  __shared__ float fg[128];
  const int t = threadIdx.x, b = blockIdx.x;
  if (t < 128) fg[t] = Fg[(size_t)b*128 + t];
  __syncthreads();
  const float* Wp = W + (size_t)b*128*1024 + t*4;
  f32x4_t acc = {0.f,0.f,0.f,0.f};
  for (int g=0; g<128; ++g){
    f32x4_t w4 = *(const f32x4_t*)(Wp + (size_t)g*1024);
    acc += w4 * fg[g];
  }
  atomicAdd(&d0a[t*4+0], acc[0]);
  atomicAdd(&d0a[t*4+1], acc[1]);
  atomicAdd(&d0a[t*4+2], acc[2]);
  atomicAdd(&d0a[t*4+3], acc[3]);
}

// d1: relu(d0+b0) @ W_d1 partials (4 blocks over g)
__global__ __launch_bounds__(256) void k_d1(const float* __restrict__ d0a, const float* __restrict__ b0,
                                            const float* __restrict__ W, float* __restrict__ d1a){
  __shared__ float x[256];
  const int t = threadIdx.x, b = blockIdx.x;
  x[t] = fmaxf(d0a[b*256 + t] + b0[b*256 + t], 0.0f);
  __syncthreads();
  float acc = 0.f;
  const float* Wp = W + (size_t)b*256*256 + t;
  for (int g=0; g<256; ++g) acc += x[g] * Wp[(size_t)g*256];
  atomicAdd(&d1a[t], acc);
}

// final: relu(d1+b1) @ W_d2, softmax -> out[8]
__global__ __launch_bounds__(256) void k_final(const float* __restrict__ d1a, const float* __restrict__ b1,
                                               const float* __restrict__ W2, float* __restrict__ outp){
  __shared__ float x[256];
  __shared__ float lg[8];
  const int t = threadIdx.x;
  x[t] = fmaxf(d1a[t] + b1[t], 0.0f);
  __syncthreads();
  if (t < 8){
    float s = 0.f;
    for (int o=0;o<256;o++) s += x[o]*W2[o*8 + t];
    lg[t] = s;
  }
  __syncthreads();
  if (t == 0){
    float mx = lg[0];
    for (int c=1;c<8;c++) mx = fmaxf(mx, lg[c]);
    float e[8], s = 0.f;
    for (int c=0;c<8;c++){ e[c] = expf(lg[c]-mx); s += e[c]; }
    for (int c=0;c<8;c++) outp[c] = e[c]/s;
  }
}

// ---------------------------------------------------------------------------
extern "C" void kernel_launch(void* const* d_in, const int* in_sizes, int n_in,
                              void* d_out, int out_size, void* d_ws, size_t ws_size,
                              hipStream_t stream)
{
  const float* F_   = (const float*)d_in[0];   // [8192,8192]
  const float* X    = (const float*)d_in[1];   // [8192,256]
  const float* We0  = (const float*)d_in[2];   // [256,256]
  const float* be0  = (const float*)d_in[3];
  const float* We1  = (const float*)d_in[4];   // [256,128]
  const float* be1  = (const float*)d_in[5];
  const float* We2  = (const float*)d_in[6];   // [128,64]
  const float* be2  = (const float*)d_in[7];
  const float* Wd0  = (const float*)d_in[8];   // [65536,1024]
  const float* bd0  = (const float*)d_in[9];
  const float* Wd1  = (const float*)d_in[10];  // [1024,256]
  const float* bd1  = (const float*)d_in[11];
  const float* Wd2  = (const float*)d_in[12];  // [256,8]
  const float* path = (const float*)d_in[13];  // [8192,8192]
  const float* mem  = (const float*)d_in[14];  // [8192,8]

  float* out_feat  = (float*)d_out;                       // [8192,64]
  float* out_force = out_feat + (size_t)8192*64;          // [8192,8192]
  float* out_prob  = out_force + (size_t)8192*8192;       // [8]

  char* ws = (char*)d_ws;
  bfu*   XT    = (bfu*)  (ws);             // [256][8192] bf16        4 MiB
  bfu*   We0T  = (bfu*)  (ws + 4194304);   // [256][256]
  bfu*   We1T  = (bfu*)  (ws + 4325376);   // [128][256]
  bfu*   We2T  = (bfu*)  (ws + 4390912);   // [64][128]
  bfu*   inpb  = (bfu*)  (ws + 4407296);   // [8192][256] bf16 (summed inp)
  bfu*   h0    = (bfu*)  (ws + 21184512);  // [8192][256] bf16
  bfu*   h1    = (bfu*)  (ws + 25378816);  // [8192][128] bf16
  bfu*   Eb    = (bfu*)  (ws + 27475968);  // [8192][64]  bf16
  float* n2    = (float*)(ws + 28524544);  // [8192]
  float* Fg    = (float*)(ws + 28557312);  // [65536]
  float* d0a   = (float*)(ws + 28819456);  // [1024]
  float* d1a   = (float*)(ws + 28823552);  // [256]

  // split-K partials live in out_force (dead until k_gram overwrites it):
  // 8 x [8192][256] fp32 = 64 MiB << 256 MiB
  float* partA = out_force;

  // zero the atomic accumulators (d0a and d1a are adjacent: 4096+1024 bytes)
  hipMemsetAsync(d0a, 0, 5120, stream);

  // bf16 B^T operands
  k_transpose<<<dim3(8,256),256,0,stream>>>(X,   XT,   8192, 256);
  k_transpose<<<dim3(8,8),  256,0,stream>>>(We0, We0T, 256,  256);
  k_transpose<<<dim3(4,8),  256,0,stream>>>(We1, We1T, 256,  128);
  k_transpose<<<dim3(2,4),  256,0,stream>>>(We2, We2T, 128,  64);

  // inp = F_ @ X   (split-K=8 -> 1024 blocks = 4 blocks/CU, fp32 partials)
  gemm_kernel<1,4,1,0><<<dim3(128,1,8),256,0,stream>>>(F_, nullptr, XT, nullptr,
                                                       partA, nullptr, 8192,256,8192,1024);
  // sum the 8 partials -> bf16 inp
  k_reduce8<<<2048,256,0,stream>>>(partA, inpb);
  // h0 = tanh(inp @ We0 + b)
  gemm_kernel<1,4,0,1><<<dim3(128,1,1),256,0,stream>>>(inpb, nullptr, We0T, be0,
                                                       nullptr, h0, 8192,256,256,256);
  // h1 = tanh(h0 @ We1 + b)
  gemm_kernel<2,2,0,1><<<dim3(64,1,1),256,0,stream>>>(h0, nullptr, We1T, be1,
                                                      nullptr, h1, 8192,128,256,256);
  // E = h1 @ We2 + b  -> fp32 (output 0) and bf16 (for Gram)
  gemm_kernel<4,1,0,2><<<dim3(32,1,1),256,0,stream>>>(h1, nullptr, We2T, be2,
                                                      out_feat, Eb, 8192,64,128,128);

  k_n2<<<2048,256,0,stream>>>(out_feat, n2);
  k_gram<<<dim3(64,64),256,0,stream>>>(Eb, n2, path, out_force);
  k_fg<<<1024,256,0,stream>>>(out_force, mem, Fg);
  k_d0<<<512,256,0,stream>>>(Fg, Wd0, d0a);
  k_d1<<<4,256,0,stream>>>(d0a, bd0, Wd1, d1a);
  k_final<<<1,256,0,stream>>>(d1a, bd1, Wd2, out_prob);
}

// Round 3
// 1064.328 us; speedup vs baseline: 1.1275x; 1.0084x over previous
//
#include <hip/hip_runtime.h>
#include <math.h>

typedef unsigned short bfu;                                     // bf16 bit pattern
typedef __attribute__((ext_vector_type(8))) short  bf16x8_t;    // MFMA A/B frag (8 bf16)
typedef __attribute__((ext_vector_type(4))) float  f32x4_t;     // MFMA C/D frag
typedef __attribute__((ext_vector_type(4))) unsigned short u16x4_t;

// fp32 -> bf16 RNE (values are finite; no NaN handling needed)
__device__ __forceinline__ short f2bf(float x){
  unsigned u = __float_as_uint(x);
  u += 0x7fffu + ((u >> 16) & 1u);
  return (short)(u >> 16);
}

// async global->LDS, 16B per lane; LDS dest is wave-uniform base + lane*16
__device__ __forceinline__ void gload_lds16(const void* g, void* l){
  __builtin_amdgcn_global_load_lds((__attribute__((address_space(1))) void*)(g),
                                   (__attribute__((address_space(3))) void*)(l), 16, 0, 0);
}

// ---------------------------------------------------------------------------
// transpose + fp32->bf16 convert: dst[c][r] = bf16(src[r][c])
__global__ __launch_bounds__(256) void k_transpose(const float* __restrict__ src,
                                                   bfu* __restrict__ dst, int R, int C){
  __shared__ float tile[32][33];
  int tx = threadIdx.x & 31, ty = threadIdx.x >> 5;
  int bc = blockIdx.x * 32, br = blockIdx.y * 32;
  #pragma unroll
  for (int i=0;i<4;i++){
    int r = br + ty + i*8, c = bc + tx;
    if (r < R && c < C) tile[ty+i*8][tx] = src[(size_t)r*C + c];
  }
  __syncthreads();
  #pragma unroll
  for (int i=0;i<4;i++){
    int c = bc + ty + i*8, r = br + tx;
    if (c < C && r < R) dst[(size_t)c*R + r] = (bfu)f2bf(tile[tx][ty+i*8]);
  }
}

// ---------------------------------------------------------------------------
// Tiled bf16 MFMA GEMM:  C[M,N] = A[M,K] @ Bt[N,K]^T   (Bt is B transposed)
// AMODE: 0 = A is bf16 (global_load_lds staging)
//        1 = A is fp32 (convert during staging)
//        2 = A is sum of two fp32 buffers (split-K partials) then convert
// EPI:   0 = store fp32 to Cf (+ blockIdx.z*M*N, split-K partial output)
//        1 = bias + tanh -> bf16 Cb
//        2 = bias -> fp32 Cf AND bf16 Cb
// Block tile BM=64*WM x BN=64*WN, 4 waves each computing 64x64, BK=32.
// LDS rows are 32 bf16 = 64B = 4 x 16B slots; content cg of row r lives at
// slot cg ^ ((r>>1)&3)  (XOR swizzle -> frag ds_read_b128 8-way -> 2-way).
// Requires N == BN, M % BM == 0, K % 32 == 0.
template<int WM, int WN, int AMODE, int EPI>
__global__ __launch_bounds__(256) void gemm_kernel(
    const void* __restrict__ Ap, const void* __restrict__ Ap2,
    const bfu* __restrict__ Bt, const float* __restrict__ bias,
    float* __restrict__ Cf, bfu* __restrict__ Cb,
    int M, int N, int K, int Ksub)
{
  constexpr int BM = 64*WM, BN = 64*WN, BK = 32;
  __shared__ bfu As[BM*BK];   // [BM][32] row-major, swizzled slots
  __shared__ bfu Bs[BN*BK];   // [BN][32] row-major, swizzled slots
  const int tid  = threadIdx.x;
  const int lane = tid & 63;
  const int w    = tid >> 6;
  const int wm   = w % WM, wn = w / WM;
  const int q    = lane >> 4, lm = lane & 15;
  const int mBase = blockIdx.x * BM;
  const int kOff0 = blockIdx.z * Ksub;
  float* Cfo = Cf + (size_t)blockIdx.z * M * N;

  // pre-swizzled 16B slot for gload_lds staging (r0 multiples of 16)
  const int cgs = (lane & 3) ^ ((lane >> 3) & 3);

  f32x4_t acc[4][4] = {};

  for (int k0 = 0; k0 < Ksub; k0 += BK){
    const int kOff = kOff0 + k0;
    // ---- stage A tile [BM][32] ----
    if constexpr (AMODE == 0){
      const bfu* A = (const bfu*)Ap;
      #pragma unroll
      for (int i=0;i<BM/64;i++){
        int r0 = w*(BM/4) + i*16;
        gload_lds16(A + (size_t)(mBase + r0 + (lane>>2))*K + kOff + cgs*8,
                    As + r0*BK);
      }
    } else {
      const float* A1 = (const float*)Ap;
      const float* A2 = (const float*)Ap2;
      #pragma unroll
      for (int i=0;i<BM/64;i++){
        int r0 = w*(BM/4) + i*16;
        int r  = r0 + (lane>>2);
        int cc = (lane&3)*8;
        int cw = cgs*8;                     // swizzled LDS slot
        size_t gix = (size_t)(mBase + r)*K + kOff + cc;
        f32x4_t x0 = *(const f32x4_t*)(A1 + gix);
        f32x4_t x1 = *(const f32x4_t*)(A1 + gix + 4);
        if constexpr (AMODE == 2){
          f32x4_t y0 = *(const f32x4_t*)(A2 + gix);
          f32x4_t y1 = *(const f32x4_t*)(A2 + gix + 4);
          x0 += y0; x1 += y1;
        }
        bf16x8_t s;
        #pragma unroll
        for (int e=0;e<4;e++){ s[e] = f2bf(x0[e]); s[e+4] = f2bf(x1[e]); }
        *(bf16x8_t*)(As + r*BK + cw) = s;
      }
    }
    // ---- stage B tile [BN][32] via global_load_lds ----
    #pragma unroll
    for (int i=0;i<BN/64;i++){
      int r0 = w*(BN/4) + i*16;
      gload_lds16(Bt + (size_t)(r0 + (lane>>2))*K + kOff + cgs*8,
                  Bs + r0*BK);
    }
    __syncthreads();
    // ---- MFMA: wave computes 64x64 via 4x4 frags of 16x16x32 ----
    bf16x8_t af[4], bfr[4];
    #pragma unroll
    for (int mf=0;mf<4;mf++){
      int row = wm*64 + mf*16 + lm;
      af[mf]  = *(const bf16x8_t*)(As + row*BK + ((q ^ ((row>>1)&3))*8));
    }
    #pragma unroll
    for (int nf=0;nf<4;nf++){
      int row = wn*64 + nf*16 + lm;
      bfr[nf] = *(const bf16x8_t*)(Bs + row*BK + ((q ^ ((row>>1)&3))*8));
    }
    #pragma unroll
    for (int mf=0;mf<4;mf++)
      #pragma unroll
      for (int nf=0;nf<4;nf++)
        acc[mf][nf] = __builtin_amdgcn_mfma_f32_16x16x32_bf16(af[mf], bfr[nf], acc[mf][nf], 0, 0, 0);
    __syncthreads();
  }
  // ---- epilogue: C/D layout col=lane&15, row=(lane>>4)*4+reg ----
  #pragma unroll
  for (int mf=0;mf<4;mf++){
    #pragma unroll
    for (int nf=0;nf<4;nf++){
      #pragma unroll
      for (int r=0;r<4;r++){
        int row = mBase + wm*64 + mf*16 + q*4 + r;
        int col = wn*64 + nf*16 + lm;       // N == BN
        float v = acc[mf][nf][r];
        size_t oix = (size_t)row*N + col;
        if constexpr (EPI == 0){
          Cfo[oix] = v;
        } else if constexpr (EPI == 1){
          v = tanhf(v + bias[col]);
          Cb[oix] = (bfu)f2bf(v);
        } else {
          v += bias[col];
          Cfo[oix] = v;
          Cb[oix] = (bfu)f2bf(v);
        }
      }
    }
  }
}

// ---------------------------------------------------------------------------
// Pipelined fp32-A GEMM for inp = F_ @ X (the big K=8192 streaming GEMM).
// Same tiling/swizzle as gemm_kernel<1,4,1,0> (BM=64, BN=256, BK=32, 4 waves)
// but double-buffered LDS with prefetch-1: loads for tile t+1 are issued
// BEFORE the MFMA of tile t, so HBM latency hides under frag-reads + MFMA +
// convert instead of being drained at a barrier every K-step.
// A-loads issued first -> their wait is a counted vmcnt (B gloads stay in
// flight); B global_load_lds drains at the single end-of-step barrier.
__global__ __launch_bounds__(256) void gemm_pipe(
    const float* __restrict__ A, const bfu* __restrict__ Bt,
    float* __restrict__ Cf, int M, int N, int K, int Ksub)
{
  __shared__ bfu As[2][64*32];    // 2 x 4 KiB
  __shared__ bfu Bs[2][256*32];   // 2 x 16 KiB  (total 40 KiB -> 4 blocks/CU)
  const int tid  = threadIdx.x;
  const int lane = tid & 63;
  const int w    = tid >> 6;
  const int q    = lane >> 4, lm = lane & 15;
  const int mBase = blockIdx.x * 64;
  const int kOff0 = blockIdx.z * Ksub;
  float* Cfo = Cf + (size_t)blockIdx.z * M * N;

  const int cgs  = (lane & 3) ^ ((lane >> 3) & 3);  // staging slot swizzle
  const int arow = w*16 + (lane >> 2);              // A stage row
  const int acol = (lane & 3) * 8;                  // A stage col (8 fp32)

  f32x4_t acc[4][4] = {};
  f32x4_t ax0, ax1;                                 // prefetched A fp32

  auto issueA = [&](int t){
    size_t gix = (size_t)(mBase + arow)*K + kOff0 + t*32 + acol;
    ax0 = *(const f32x4_t*)(A + gix);
    ax1 = *(const f32x4_t*)(A + gix + 4);
  };
  auto writeA = [&](bfu* dst){
    bf16x8_t s;
    #pragma unroll
    for (int e=0;e<4;e++){ s[e] = f2bf(ax0[e]); s[e+4] = f2bf(ax1[e]); }
    *(bf16x8_t*)(dst + arow*32 + cgs*8) = s;
  };
  auto issueB = [&](int t, bfu* dst){
    #pragma unroll
    for (int i=0;i<4;i++){
      int r0 = w*64 + i*16;
      gload_lds16(Bt + (size_t)(r0 + (lane>>2))*K + kOff0 + t*32 + cgs*8,
                  dst + r0*32);
    }
  };

  const int nt = Ksub / 32;
  // prologue: tile 0 into buffer 0
  issueA(0);
  issueB(0, Bs[0]);
  writeA(As[0]);
  __syncthreads();                                  // B(0) resident

  for (int t = 0; t < nt; ++t){
    const int cur = t & 1, nxt = cur ^ 1;
    if (t+1 < nt){
      issueA(t+1);                                  // oldest -> counted wait at writeA
      issueB(t+1, Bs[nxt]);                         // drains at end-of-step barrier
    }
    bf16x8_t af[4], bfr[4];
    #pragma unroll
    for (int mf=0;mf<4;mf++){
      int row = mf*16 + lm;
      af[mf]  = *(const bf16x8_t*)(&As[cur][row*32 + ((q ^ ((row>>1)&3))*8)]);
    }
    #pragma unroll
    for (int nf=0;nf<4;nf++){
      int row = w*64 + nf*16 + lm;
      bfr[nf] = *(const bf16x8_t*)(&Bs[cur][row*32 + ((q ^ ((row>>1)&3))*8)]);
    }
    #pragma unroll
    for (int mf=0;mf<4;mf++)
      #pragma unroll
      for (int nf=0;nf<4;nf++)
        acc[mf][nf] = __builtin_amdgcn_mfma_f32_16x16x32_bf16(af[mf], bfr[nf], acc[mf][nf], 0, 0, 0);
    if (t+1 < nt) writeA(As[nxt]);                  // cvt + ds_write next A
    __syncthreads();
  }

  #pragma unroll
  for (int mf=0;mf<4;mf++){
    #pragma unroll
    for (int nf=0;nf<4;nf++){
      #pragma unroll
      for (int r=0;r<4;r++){
        int row = mBase + mf*16 + q*4 + r;
        int col = w*64 + nf*16 + lm;
        Cfo[(size_t)row*N + col] = acc[mf][nf][r];
      }
    }
  }
}

// ---------------------------------------------------------------------------
// sum 8 split-K fp32 partials [8][8192*256] -> bf16 [8192][256]
// one f32x4 per thread, fully coalesced; ~68 MB traffic total
__global__ __launch_bounds__(256) void k_reduce8(const float* __restrict__ P,
                                                 bfu* __restrict__ dst){
  const size_t idx = (size_t)blockIdx.x*256 + threadIdx.x;   // f32x4 index
  const size_t stride4 = (size_t)8192*256/4;                 // f32x4 per partial
  f32x4_t a = *(const f32x4_t*)(P + idx*4);
  #pragma unroll
  for (int s=1;s<8;s++){
    f32x4_t b = *(const f32x4_t*)(P + (stride4*s + idx)*4);
    a += b;
  }
  u16x4_t o;
  #pragma unroll
  for (int e=0;e<4;e++) o[e] = (unsigned short)f2bf(a[e]);
  *(u16x4_t*)(dst + idx*4) = o;
}

// ---------------------------------------------------------------------------
// row squared-norms of E [8192][64] (fp32): one wave per row
__global__ __launch_bounds__(256) void k_n2(const float* __restrict__ E, float* __restrict__ n2){
  int row  = blockIdx.x*4 + (threadIdx.x >> 6);
  int lane = threadIdx.x & 63;
  float v = E[(size_t)row*64 + lane];
  v *= v;
  #pragma unroll
  for (int off=32; off>0; off>>=1) v += __shfl_down(v, off);
  if (lane == 0) n2[row] = v;
}

// ---------------------------------------------------------------------------
// new_force[i][j] = sqrt(max(n2[i]+n2[j]-2*dot(Ei,Ej),0)) * path[i][j]; diag=0
// 128x128 tile per block, Gram via bf16 MFMA (K=64).
// XOR-swizzled E staging (16-way bank conflict -> free) and an
// LDS-transposed epilogue: acc is restaged through a [2][32][132] f32 tile
// (2 passes, aliasing the stage buffers) so path loads / NF stores are
// fully coalesced float4 (1KB per wave instruction).
__global__ __launch_bounds__(256) void k_gram(const bfu* __restrict__ Eb, const float* __restrict__ n2,
                                              const float* __restrict__ path, float* __restrict__ NF)
{
  __shared__ alignas(16) char smraw[33792];           // max(Ei+Ej 32KiB, gram 33KiB)
  bfu*   Ei   = (bfu*)smraw;                          // [128][64] bf16, swizzled
  bfu*   Ej   = (bfu*)(smraw + 16384);                // [128][64] bf16, swizzled
  float* gram = (float*)smraw;                        // [2][32][132] f32
  __shared__ float n2i[128], n2j[128];

  const int tid = threadIdx.x, lane = tid & 63, w = tid >> 6;
  const int ib = blockIdx.x * 128, jb = blockIdx.y * 128;
  if (tid < 128) n2i[tid] = n2[ib + tid];
  else           n2j[tid-128] = n2[jb + tid - 128];

  // ---- stage Ei/Ej: LDS layout puts content cg of row r at slot cg^(r&7)
  // (gload_lds writes linearly -> pre-swizzle the GLOBAL source per lane)
  {
    int rsub = lane >> 3;                 // 0..7 (row within 8-row group)
    int cg   = (lane & 7) ^ rsub;         // 16B slot -> source column group
    #pragma unroll
    for (int i=0;i<4;i++){
      int r0 = w*32 + i*8;                // multiple of 8
      int r  = r0 + rsub;
      gload_lds16(Eb + (size_t)(ib + r)*64 + cg*8, Ei + r0*64);
      gload_lds16(Eb + (size_t)(jb + r)*64 + cg*8, Ej + r0*64);
    }
  }
  __syncthreads();

  const int q = lane >> 4, lm = lane & 15;
  const int wm = w & 1, wn = w >> 1;
  f32x4_t acc[4][4] = {};
  #pragma unroll
  for (int ks=0; ks<2; ks++){
    bf16x8_t af[4], bfr[4];
    #pragma unroll
    for (int mf=0;mf<4;mf++){
      int row = wm*64 + mf*16 + lm;
      int cg  = (ks*4 + q) ^ (row & 7);
      af[mf]  = *(const bf16x8_t*)(Ei + row*64 + cg*8);
    }
    #pragma unroll
    for (int nf=0;nf<4;nf++){
      int row = wn*64 + nf*16 + lm;
      int cg  = (ks*4 + q) ^ (row & 7);
      bfr[nf] = *(const bf16x8_t*)(Ej + row*64 + cg*8);
    }
    #pragma unroll
    for (int mf=0;mf<4;mf++)
      #pragma unroll
      for (int nf=0;nf<4;nf++)
        acc[mf][nf] = __builtin_amdgcn_mfma_f32_16x16x32_bf16(af[mf], bfr[nf], acc[mf][nf], 0, 0, 0);
  }

  // ---- epilogue: 2 passes; pass p covers tile rows {wm*64 + p*32 + 0..31}
  #pragma unroll
  for (int p=0; p<2; p++){
    __syncthreads();                       // stage reads (p=0) / pass reads (p=1) done
    // scatter acc into f32 LDS tile: gram[s=wm][rloc][col], stride 132 (pad)
    #pragma unroll
    for (int mh=0; mh<2; mh++){
      int mf   = 2*p + mh;
      int rbas = mh*16 + q*4;
      #pragma unroll
      for (int nf=0; nf<4; nf++){
        int col = wn*64 + nf*16 + lm;
        #pragma unroll
        for (int r=0;r<4;r++)
          gram[(wm*32 + rbas + r)*132 + col] = acc[mf][nf][r];
      }
    }
    __syncthreads();
    // coalesced sweep: 64 rows x 128 cols, float4 per lane
    #pragma unroll
    for (int it=0; it<8; it++){
      int flat = it*256 + tid;
      int rr   = flat >> 5;                // 0..63
      int s    = rr >> 5;                  // 0..1 (wm half)
      int rloc = rr & 31;
      int colg = (flat & 31)*4;
      int trow = s*64 + p*32 + rloc;
      int gi   = ib + trow;
      int gj   = jb + colg;
      f32x4_t g4 = *(const f32x4_t*)&gram[(s*32 + rloc)*132 + colg];
      f32x4_t nj = *(const f32x4_t*)&n2j[colg];
      float   ni = n2i[trow];
      f32x4_t pv = *(const f32x4_t*)(path + (size_t)gi*8192 + gj);
      f32x4_t outv;
      #pragma unroll
      for (int e=0;e<4;e++){
        float sq = ni + nj[e] - 2.0f*g4[e];
        float dv = sq > 0.0f ? sqrtf(sq) : 0.0f;
        if (gi == gj + e) dv = 0.0f;       // reference diagonal is exactly 0
        outv[e] = dv * pv[e];
      }
      *(f32x4_t*)(NF + (size_t)gi*8192 + gj) = outv;
    }
  }
}

// ---------------------------------------------------------------------------
// Fg[i][c] = sum_j NF[i][j]*members[j][c]; block handles 8 rows, full j-range
__global__ __launch_bounds__(256) void k_fg(const float* __restrict__ NF, const float* __restrict__ mem,
                                            float* __restrict__ Fg){
  const int t = threadIdx.x;
  const int i0 = blockIdx.x * 8;
  float acc[8][8] = {};
  for (int p=0;p<8;p++){
    int j4 = (p*256 + t)*4;
    float mm[4][8];
    #pragma unroll
    for (int qq=0;qq<4;qq++){
      f32x4_t a = *(const f32x4_t*)(mem + (size_t)(j4+qq)*8);
      f32x4_t b = *(const f32x4_t*)(mem + (size_t)(j4+qq)*8 + 4);
      #pragma unroll
      for (int c=0;c<4;c++){ mm[qq][c] = a[c]; mm[qq][c+4] = b[c]; }
    }
    #pragma unroll
    for (int r=0;r<8;r++){
      f32x4_t f = *(const f32x4_t*)(NF + (size_t)(i0+r)*8192 + j4);
      #pragma unroll
      for (int qq=0;qq<4;qq++)
        #pragma unroll
        for (int c=0;c<8;c++)
          acc[r][c] += f[qq]*mm[qq][c];
    }
  }
  __shared__ float red[4][64];
  int lane = t & 63, w = t >> 6;
  #pragma unroll
  for (int rc=0; rc<64; rc++){
    float v = acc[rc>>3][rc&7];
    #pragma unroll
    for (int off=32; off>0; off>>=1) v += __shfl_down(v, off);
    if (lane == 0) red[w][rc] = v;
  }
  __syncthreads();
  if (t < 64) Fg[(size_t)i0*8 + t] = red[0][t]+red[1][t]+red[2][t]+red[3][t];
}

// ---------------------------------------------------------------------------
// d0 partial GEMV: block b covers g in [b*128,b*128+128); 256 thr x 4 outputs
__global__ __launch_bounds__(256) void k_d0(const float* __restrict__ Fg, const float* __restrict__ W,
                                            float* __restrict__ d0a){
  __shared__ float fg[128];
  const int t = threadIdx.x, b = blockIdx.x;
  if (t < 128) fg[t] = Fg[(size_t)b*128 + t];
  __syncthreads();
  const float* Wp = W + (size_t)b*128*1024 + t*4;
  f32x4_t acc = {0.f,0.f,0.f,0.f};
  for (int g=0; g<128; ++g){
    f32x4_t w4 = *(const f32x4_t*)(Wp + (size_t)g*1024);
    acc += w4 * fg[g];
  }
  atomicAdd(&d0a[t*4+0], acc[0]);
  atomicAdd(&d0a[t*4+1], acc[1]);
  atomicAdd(&d0a[t*4+2], acc[2]);
  atomicAdd(&d0a[t*4+3], acc[3]);
}

// d1: relu(d0+b0) @ W_d1 partials (4 blocks over g)
__global__ __launch_bounds__(256) void k_d1(const float* __restrict__ d0a, const float* __restrict__ b0,
                                            const float* __restrict__ W, float* __restrict__ d1a){
  __shared__ float x[256];
  const int t = threadIdx.x, b = blockIdx.x;
  x[t] = fmaxf(d0a[b*256 + t] + b0[b*256 + t], 0.0f);
  __syncthreads();
  float acc = 0.f;
  const float* Wp = W + (size_t)b*256*256 + t;
  for (int g=0; g<256; ++g) acc += x[g] * Wp[(size_t)g*256];
  atomicAdd(&d1a[t], acc);
}

// final: relu(d1+b1) @ W_d2, softmax -> out[8]
__global__ __launch_bounds__(256) void k_final(const float* __restrict__ d1a, const float* __restrict__ b1,
                                               const float* __restrict__ W2, float* __restrict__ outp){
  __shared__ float x[256];
  __shared__ float lg[8];
  const int t = threadIdx.x;
  x[t] = fmaxf(d1a[t] + b1[t], 0.0f);
  __syncthreads();
  if (t < 8){
    float s = 0.f;
    for (int o=0;o<256;o++) s += x[o]*W2[o*8 + t];
    lg[t] = s;
  }
  __syncthreads();
  if (t == 0){
    float mx = lg[0];
    for (int c=1;c<8;c++) mx = fmaxf(mx, lg[c]);
    float e[8], s = 0.f;
    for (int c=0;c<8;c++){ e[c] = expf(lg[c]-mx); s += e[c]; }
    for (int c=0;c<8;c++) outp[c] = e[c]/s;
  }
}

// ---------------------------------------------------------------------------
extern "C" void kernel_launch(void* const* d_in, const int* in_sizes, int n_in,
                              void* d_out, int out_size, void* d_ws, size_t ws_size,
                              hipStream_t stream)
{
  const float* F_   = (const float*)d_in[0];   // [8192,8192]
  const float* X    = (const float*)d_in[1];   // [8192,256]
  const float* We0  = (const float*)d_in[2];   // [256,256]
  const float* be0  = (const float*)d_in[3];
  const float* We1  = (const float*)d_in[4];   // [256,128]
  const float* be1  = (const float*)d_in[5];
  const float* We2  = (const float*)d_in[6];   // [128,64]
  const float* be2  = (const float*)d_in[7];
  const float* Wd0  = (const float*)d_in[8];   // [65536,1024]
  const float* bd0  = (const float*)d_in[9];
  const float* Wd1  = (const float*)d_in[10];  // [1024,256]
  const float* bd1  = (const float*)d_in[11];
  const float* Wd2  = (const float*)d_in[12];  // [256,8]
  const float* path = (const float*)d_in[13];  // [8192,8192]
  const float* mem  = (const float*)d_in[14];  // [8192,8]

  float* out_feat  = (float*)d_out;                       // [8192,64]
  float* out_force = out_feat + (size_t)8192*64;          // [8192,8192]
  float* out_prob  = out_force + (size_t)8192*8192;       // [8]

  char* ws = (char*)d_ws;
  bfu*   XT    = (bfu*)  (ws);             // [256][8192] bf16        4 MiB
  bfu*   We0T  = (bfu*)  (ws + 4194304);   // [256][256]
  bfu*   We1T  = (bfu*)  (ws + 4325376);   // [128][256]
  bfu*   We2T  = (bfu*)  (ws + 4390912);   // [64][128]
  bfu*   inpb  = (bfu*)  (ws + 4407296);   // [8192][256] bf16 (summed inp)
  bfu*   h0    = (bfu*)  (ws + 21184512);  // [8192][256] bf16
  bfu*   h1    = (bfu*)  (ws + 25378816);  // [8192][128] bf16
  bfu*   Eb    = (bfu*)  (ws + 27475968);  // [8192][64]  bf16
  float* n2    = (float*)(ws + 28524544);  // [8192]
  float* Fg    = (float*)(ws + 28557312);  // [65536]
  float* d0a   = (float*)(ws + 28819456);  // [1024]
  float* d1a   = (float*)(ws + 28823552);  // [256]

  // split-K partials live in out_force (dead until k_gram overwrites it):
  // 8 x [8192][256] fp32 = 64 MiB << 256 MiB
  float* partA = out_force;

  // zero the atomic accumulators (d0a and d1a are adjacent: 4096+1024 bytes)
  hipMemsetAsync(d0a, 0, 5120, stream);

  // bf16 B^T operands
  k_transpose<<<dim3(8,256),256,0,stream>>>(X,   XT,   8192, 256);
  k_transpose<<<dim3(8,8),  256,0,stream>>>(We0, We0T, 256,  256);
  k_transpose<<<dim3(4,8),  256,0,stream>>>(We1, We1T, 256,  128);
  k_transpose<<<dim3(2,4),  256,0,stream>>>(We2, We2T, 128,  64);

  // inp = F_ @ X   (pipelined, split-K=8 -> 1024 blocks = 4/CU, fp32 partials)
  gemm_pipe<<<dim3(128,1,8),256,0,stream>>>(F_, XT, partA, 8192,256,8192,1024);
  // sum the 8 partials -> bf16 inp
  k_reduce8<<<2048,256,0,stream>>>(partA, inpb);
  // h0 = tanh(inp @ We0 + b)
  gemm_kernel<1,4,0,1><<<dim3(128,1,1),256,0,stream>>>(inpb, nullptr, We0T, be0,
                                                       nullptr, h0, 8192,256,256,256);
  // h1 = tanh(h0 @ We1 + b)
  gemm_kernel<2,2,0,1><<<dim3(64,1,1),256,0,stream>>>(h0, nullptr, We1T, be1,
                                                      nullptr, h1, 8192,128,256,256);
  // E = h1 @ We2 + b  -> fp32 (output 0) and bf16 (for Gram)
  gemm_kernel<4,1,0,2><<<dim3(32,1,1),256,0,stream>>>(h1, nullptr, We2T, be2,
                                                      out_feat, Eb, 8192,64,128,128);

  k_n2<<<2048,256,0,stream>>>(out_feat, n2);
  k_gram<<<dim3(64,64),256,0,stream>>>(Eb, n2, path, out_force);
  k_fg<<<1024,256,0,stream>>>(out_force, mem, Fg);
  k_d0<<<512,256,0,stream>>>(Fg, Wd0, d0a);
  k_d1<<<4,256,0,stream>>>(d0a, bd0, Wd1, d1a);
  k_final<<<1,256,0,stream>>>(d1a, bd1, Wd2, out_prob);
}